// Round 1
// baseline (803.900 us; speedup 1.0000x reference)
//
#include <hip/hip_runtime.h>

// DonutSwinAttention: hs[2048,49,384] fp32 -> out[2048,49,384] fp32
// Pipeline: prep(X->bf16, W^T->bf16, rpb gather) ; QKV MFMA GEMM ; vector attention ; O-proj MFMA GEMM
// Internal compute in bf16 (threshold 6.56e-3 permits; est. max err ~2e-3).

typedef unsigned short u16;
typedef short bf16x8 __attribute__((ext_vector_type(8)));   // MFMA A/B operand (8 bf16)
typedef float f32x4  __attribute__((ext_vector_type(4)));   // MFMA C/D
typedef u16   u16x8  __attribute__((ext_vector_type(8)));
typedef u16   u16x4  __attribute__((ext_vector_type(4)));

#define NWIN   2048
#define SEQ    49
#define DIM    384
#define NH     12
#define HD     32
#define MTOT   (NWIN*SEQ)      // 100352 = 784*128
#define WELEM  (DIM*DIM)       // 147456

__device__ __forceinline__ u16 f2b(float f) {               // fp32 -> bf16 RTN-even
    union { float f; unsigned u; } c; c.f = f;
    unsigned u = c.u;
    u += 0x7FFFu + ((u >> 16) & 1u);
    return (u16)(u >> 16);
}
__device__ __forceinline__ float b2f(u16 b) {
    union { unsigned u; float f; } c; c.u = ((unsigned)b) << 16;
    return c.f;
}

// ---------------- prep kernels ----------------
__global__ __launch_bounds__(256) void prep_x(const float* __restrict__ X, u16* __restrict__ Xb) {
    int i = blockIdx.x * 256 + threadIdx.x;      // 9,633,792 float4s, exact
    float4 v = ((const float4*)X)[i];
    u16x4 o; o[0]=f2b(v.x); o[1]=f2b(v.y); o[2]=f2b(v.z); o[3]=f2b(v.w);
    ((u16x4*)Xb)[i] = o;
}

__global__ __launch_bounds__(256) void prep_w(const float* __restrict__ qW, const float* __restrict__ kW,
                                              const float* __restrict__ vW, const float* __restrict__ oW,
                                              u16* __restrict__ Wt) {
    int t = blockIdx.x * 256 + threadIdx.x;      // 589,824 exact; 576 blocks per matrix (uniform)
    int m = t / WELEM; int rem = t - m * WELEM;
    int k = rem / DIM; int n = rem - k * DIM;
    const float* src = (m==0) ? qW : (m==1) ? kW : (m==2) ? vW : oW;
    Wt[m*WELEM + n*DIM + k] = f2b(src[rem]);     // Wt[m][n][k] = W[k][n]
}

__global__ __launch_bounds__(256) void prep_rpb(const float* __restrict__ bt, const int* __restrict__ ridx,
                                                float* __restrict__ rpb) {
    int t = blockIdx.x * 256 + threadIdx.x;
    if (t >= NH * SEQ * SEQ) return;
    int h = t / (SEQ*SEQ); int st = t - h * (SEQ*SEQ);
    rpb[t] = bt[ridx[st] * NH + h];              // rpb[h][s][t]
}

// ---------------- shared GEMM mainloop: 128x128 tile, K=384, BK=64, 4 waves (2x2) ----------------
// A: [M][384] bf16 row-major; B: W^T [N][384] bf16 (row = out col). Reg-staged LDS this round.
__device__ __forceinline__ void stage_tile(const u16* __restrict__ g0, u16* __restrict__ lds, int tid) {
    #pragma unroll
    for (int i = 0; i < 4; i++) {
        int j = tid * 4 + i;                     // 1024 chunks of 8 u16
        int row = j >> 3, c8 = (j & 7) * 8;
        u16x8 v = *(const u16x8*)(g0 + row * DIM + c8);
        *(u16x8*)&lds[row * 64 + c8] = v;
    }
}

__device__ __forceinline__ void gemm_tile(const u16* __restrict__ Abase, const u16* __restrict__ Bbase,
                                          f32x4 (&acc)[4][4]) {
    __shared__ __align__(16) u16 As[128 * 64];
    __shared__ __align__(16) u16 Bs[128 * 64];
    const int tid = threadIdx.x, wave = tid >> 6, lane = tid & 63;
    const int wm = wave >> 1, wn = wave & 1;
    for (int kt = 0; kt < 6; kt++) {
        __syncthreads();                          // previous iter's ds_reads done before overwrite
        stage_tile(Abase + kt * 64, As, tid);
        stage_tile(Bbase + kt * 64, Bs, tid);
        __syncthreads();
        #pragma unroll
        for (int kk = 0; kk < 2; kk++) {
            const int co = kk * 32 + (lane >> 4) * 8;   // k-offset for this lane
            bf16x8 a[4], b[4];
            #pragma unroll
            for (int mi = 0; mi < 4; mi++)
                a[mi] = *(const bf16x8*)&As[(wm * 64 + mi * 16 + (lane & 15)) * 64 + co];
            #pragma unroll
            for (int ni = 0; ni < 4; ni++)
                b[ni] = *(const bf16x8*)&Bs[(wn * 64 + ni * 16 + (lane & 15)) * 64 + co];
            #pragma unroll
            for (int mi = 0; mi < 4; mi++)
                #pragma unroll
                for (int ni = 0; ni < 4; ni++)
                    acc[mi][ni] = __builtin_amdgcn_mfma_f32_16x16x32_bf16(a[mi], b[ni], acc[mi][ni], 0, 0, 0);
        }
    }
}

// ---------------- QKV projection ----------------
__global__ __launch_bounds__(256) void qkv_gemm(const u16* __restrict__ Xb, const u16* __restrict__ Wt,
                                                const float* __restrict__ qb, const float* __restrict__ kb,
                                                const float* __restrict__ vb,
                                                u16* __restrict__ Qo, u16* __restrict__ Ko, u16* __restrict__ Vo) {
    const int mBase = blockIdx.x * 128;
    const int nt = blockIdx.y;                    // 0..8 ; 3 n-tiles per projection
    const int proj = nt / 3, nBase = (nt - proj * 3) * 128;
    f32x4 acc[4][4];
    #pragma unroll
    for (int mi = 0; mi < 4; mi++)
        #pragma unroll
        for (int ni = 0; ni < 4; ni++) { f32x4 z = {0.f,0.f,0.f,0.f}; acc[mi][ni] = z; }

    gemm_tile(Xb + mBase * DIM, Wt + proj * WELEM + nBase * DIM, acc);

    const float* bias = (proj==0) ? qb : (proj==1) ? kb : vb;
    u16* Out          = (proj==0) ? Qo : (proj==1) ? Ko : Vo;
    const float scale = (proj==0) ? 0.17677669529663687f : 1.0f;   // fold 1/sqrt(32) into Q
    const int tid = threadIdx.x, wave = tid >> 6, lane = tid & 63;
    const int wm = wave >> 1, wn = wave & 1;

    float bias4[4]; int hh[4], dd[4];
    #pragma unroll
    for (int ni = 0; ni < 4; ni++) {
        int nin = nBase + wn * 64 + ni * 16 + (lane & 15);
        bias4[ni] = bias[nin]; hh[ni] = nin >> 5; dd[ni] = nin & 31;
    }
    #pragma unroll
    for (int mi = 0; mi < 4; mi++) {
        #pragma unroll
        for (int j = 0; j < 4; j++) {
            int gm = mBase + wm * 64 + mi * 16 + ((lane >> 4) << 2) + j;
            int bw = gm / SEQ, s = gm - bw * SEQ;
            int rowbase = (bw * (NH*SEQ) + s) * HD;           // + h*SEQ*HD + d
            #pragma unroll
            for (int ni = 0; ni < 4; ni++) {
                float val = (acc[mi][ni][j] + bias4[ni]) * scale;
                Out[rowbase + hh[ni] * (SEQ*HD) + dd[ni]] = f2b(val);
            }
        }
    }
}

// ---------------- attention (vector VALU this round) ----------------
__global__ __launch_bounds__(256) void attn_kernel(const u16* __restrict__ Qb, const u16* __restrict__ Kb,
                                                   const u16* __restrict__ Vb, const float* __restrict__ rpb,
                                                   const float* __restrict__ mask, u16* __restrict__ Ctx) {
    const int w = blockIdx.x, h = blockIdx.y;
    const int tid = threadIdx.x, wave = tid >> 6, lane = tid & 63;
    __shared__ __align__(16) float q_lds[SEQ][32];
    __shared__ float v_lds[SEQ][33];              // +1 pad: PV reads conflict-free
    __shared__ float p_lds[4][64];

    const u16* Qp = Qb + (w * NH + h) * (SEQ*HD);
    const u16* Kp = Kb + (w * NH + h) * (SEQ*HD);
    const u16* Vp = Vb + (w * NH + h) * (SEQ*HD);

    for (int i = tid; i < SEQ*HD; i += 256) q_lds[i >> 5][i & 31] = b2f(Qp[i]);
    for (int i = tid; i < SEQ*HD; i += 256) v_lds[i >> 5][i & 31] = b2f(Vp[i]);

    float kr[32];                                 // lane t caches k[t][:]
    const int t = lane;
    if (t < SEQ) {
        #pragma unroll
        for (int i = 0; i < 4; i++) {
            u16x8 kv = *(const u16x8*)&Kp[t * HD + i * 8];
            #pragma unroll
            for (int jj = 0; jj < 8; jj++) kr[i * 8 + jj] = b2f(kv[jj]);
        }
    } else {
        #pragma unroll
        for (int d0 = 0; d0 < 32; d0++) kr[d0] = 0.f;
    }
    __syncthreads();

    const float* rp = rpb + h * (SEQ*SEQ);
    const float* mp = mask + (w & 63) * (SEQ*SEQ);

    for (int s = wave; s < SEQ; s += 4) {
        float S = 0.f;
        #pragma unroll
        for (int d4 = 0; d4 < 8; d4++) {
            float4 qv = *(const float4*)&q_lds[s][d4 * 4];   // broadcast read
            S += qv.x * kr[d4*4] + qv.y * kr[d4*4+1] + qv.z * kr[d4*4+2] + qv.w * kr[d4*4+3];
        }
        float add = (t < SEQ) ? (rp[s * SEQ + t] + mp[s * SEQ + t]) : 0.f;
        S = (t < SEQ) ? (S + add) : -1e30f;
        float m = S;
        #pragma unroll
        for (int off = 1; off < 64; off <<= 1) m = fmaxf(m, __shfl_xor(m, off));
        float p = __expf(S - m);                  // lanes t>=49 -> exp(-1e30)=0
        float sum = p;
        #pragma unroll
        for (int off = 1; off < 64; off <<= 1) sum += __shfl_xor(sum, off);
        p /= sum;
        p_lds[wave][lane] = p;
        asm volatile("s_waitcnt lgkmcnt(0)" ::: "memory");   // wave-local LDS write->read ordering

        const int d = lane & 31, half = lane >> 5;
        const int t0 = half ? 25 : 0, tn = half ? 24 : 25;
        float acc = 0.f;
        for (int i = 0; i < tn; i++) {
            int t2 = t0 + i;
            acc += p_lds[wave][t2] * v_lds[t2][d];
        }
        acc += __shfl_xor(acc, 32);               // combine halves
        if (lane < 32) Ctx[(w * SEQ + s) * DIM + h * HD + d] = f2b(acc);
    }
}

// ---------------- output projection ----------------
__global__ __launch_bounds__(256) void oproj_gemm(const u16* __restrict__ Cb, const u16* __restrict__ Wo,
                                                  const float* __restrict__ ob, float* __restrict__ out) {
    const int mBase = blockIdx.x * 128, nBase = blockIdx.y * 128;
    f32x4 acc[4][4];
    #pragma unroll
    for (int mi = 0; mi < 4; mi++)
        #pragma unroll
        for (int ni = 0; ni < 4; ni++) { f32x4 z = {0.f,0.f,0.f,0.f}; acc[mi][ni] = z; }

    gemm_tile(Cb + mBase * DIM, Wo + nBase * DIM, acc);

    const int tid = threadIdx.x, wave = tid >> 6, lane = tid & 63;
    const int wm = wave >> 1, wn = wave & 1;
    float ob4[4]; int gn4[4];
    #pragma unroll
    for (int ni = 0; ni < 4; ni++) {
        gn4[ni] = nBase + wn * 64 + ni * 16 + (lane & 15);
        ob4[ni] = ob[gn4[ni]];
    }
    #pragma unroll
    for (int mi = 0; mi < 4; mi++) {
        #pragma unroll
        for (int j = 0; j < 4; j++) {
            int gm = mBase + wm * 64 + mi * 16 + ((lane >> 4) << 2) + j;
            #pragma unroll
            for (int ni = 0; ni < 4; ni++)
                out[gm * DIM + gn4[ni]] = acc[mi][ni][j] + ob4[ni];
        }
    }
}

// ---------------- launch ----------------
extern "C" void kernel_launch(void* const* d_in, const int* in_sizes, int n_in,
                              void* d_out, int out_size, void* d_ws, size_t ws_size,
                              hipStream_t stream) {
    const float* hs   = (const float*)d_in[0];
    const float* mask = (const float*)d_in[1];
    const float* qW   = (const float*)d_in[2];
    const float* qb   = (const float*)d_in[3];
    const float* kW   = (const float*)d_in[4];
    const float* kb   = (const float*)d_in[5];
    const float* vW   = (const float*)d_in[6];
    const float* vb   = (const float*)d_in[7];
    const float* oW   = (const float*)d_in[8];
    const float* ob   = (const float*)d_in[9];
    const float* bt   = (const float*)d_in[10];
    const int*   ridx = (const int*)d_in[11];
    float* out = (float*)d_out;

    char* ws = (char*)d_ws;
    // layout (bytes): Xbf 77,070,336 (aliased by Ctx after QKV) | Q | K | V | Wt 1,179,648 | rpb 115,248
    u16* Xb   = (u16*)(ws);
    u16* Ctx  = (u16*)(ws);                       // alias: X dead after qkv_gemm (stream-ordered)
    u16* Qb   = (u16*)(ws + 77070336);
    u16* Kb   = (u16*)(ws + 154140672);
    u16* Vb   = (u16*)(ws + 231211008);
    u16* Wt   = (u16*)(ws + 308281344);
    float* rpb = (float*)(ws + 309460992);        // total 309,576,240 B

    prep_x  <<<37632, 256, 0, stream>>>(hs, Xb);
    prep_w  <<<2304, 256, 0, stream>>>(qW, kW, vW, oW, Wt);
    prep_rpb<<<113, 256, 0, stream>>>(bt, ridx, rpb);
    qkv_gemm<<<dim3(784, 9), 256, 0, stream>>>(Xb, Wt, qb, kb, vb, Qb, Kb, Vb);
    attn_kernel<<<dim3(NWIN, NH), 256, 0, stream>>>(Qb, Kb, Vb, rpb, mask, Ctx);
    oproj_gemm<<<dim3(784, 3), 256, 0, stream>>>(Ctx, Wt + 3 * WELEM, ob, out);
}

// Round 2
// 394.776 us; speedup vs baseline: 2.0363x; 2.0363x over previous
//
#include <hip/hip_runtime.h>

// DonutSwinAttention: hs[2048,49,384] fp32 -> out[2048,49,384] fp32
// Pipeline: prep(X->bf16, W^T->bf16, rpb gather) ; QKV MFMA GEMM ; MFMA attention ; O-proj MFMA GEMM

typedef unsigned short u16;
typedef unsigned int   u32;
typedef short bf16x8 __attribute__((ext_vector_type(8)));   // MFMA A/B operand (8 bf16)
typedef float f32x4  __attribute__((ext_vector_type(4)));   // MFMA C/D
typedef u16   u16x8  __attribute__((ext_vector_type(8)));
typedef u16   u16x4  __attribute__((ext_vector_type(4)));

#define NWIN   2048
#define SEQ    49
#define DIM    384
#define NH     12
#define HD     32
#define MTOT   (NWIN*SEQ)      // 100352 = 784*128
#define WELEM  (DIM*DIM)       // 147456

__device__ __forceinline__ u16 f2b(float f) {               // fp32 -> bf16 RTN-even
    union { float f; unsigned u; } c; c.f = f;
    unsigned u = c.u;
    u += 0x7FFFu + ((u >> 16) & 1u);
    return (u16)(u >> 16);
}

// ---------------- prep kernels ----------------
__global__ __launch_bounds__(256) void prep_x(const float* __restrict__ X, u16* __restrict__ Xb) {
    int i = blockIdx.x * 256 + threadIdx.x;      // 9,633,792 float4s, exact
    float4 v = ((const float4*)X)[i];
    u16x4 o; o[0]=f2b(v.x); o[1]=f2b(v.y); o[2]=f2b(v.z); o[3]=f2b(v.w);
    ((u16x4*)Xb)[i] = o;
}

__global__ __launch_bounds__(256) void prep_w(const float* __restrict__ qW, const float* __restrict__ kW,
                                              const float* __restrict__ vW, const float* __restrict__ oW,
                                              u16* __restrict__ Wt) {
    int t = blockIdx.x * 256 + threadIdx.x;      // 589,824 exact
    int m = t / WELEM; int rem = t - m * WELEM;
    int k = rem / DIM; int n = rem - k * DIM;
    const float* src = (m==0) ? qW : (m==1) ? kW : (m==2) ? vW : oW;
    Wt[m*WELEM + n*DIM + k] = f2b(src[rem]);     // Wt[m][n][k] = W[k][n]
}

__global__ __launch_bounds__(256) void prep_rpb(const float* __restrict__ bt, const int* __restrict__ ridx,
                                                float* __restrict__ rpb) {
    int t = blockIdx.x * 256 + threadIdx.x;
    if (t >= NH * SEQ * SEQ) return;
    int h = t / (SEQ*SEQ); int st = t - h * (SEQ*SEQ);
    rpb[t] = bt[ridx[st] * NH + h];              // rpb[h][s][t]
}

// ---------------- shared GEMM mainloop: 128x128 tile, K=384, BK=64, 4 waves (2x2) ----------------
__device__ __forceinline__ void stage_tile(const u16* __restrict__ g0, u16* __restrict__ lds, int tid) {
    #pragma unroll
    for (int i = 0; i < 4; i++) {
        int j = tid * 4 + i;                     // 1024 chunks of 8 u16
        int row = j >> 3, c8 = (j & 7) * 8;
        u16x8 v = *(const u16x8*)(g0 + row * DIM + c8);
        *(u16x8*)&lds[row * 64 + c8] = v;
    }
}

__device__ __forceinline__ void gemm_tile(const u16* __restrict__ Abase, const u16* __restrict__ Bbase,
                                          f32x4 (&acc)[4][4]) {
    __shared__ __align__(16) u16 As[128 * 64];
    __shared__ __align__(16) u16 Bs[128 * 64];
    const int tid = threadIdx.x, wave = tid >> 6, lane = tid & 63;
    const int wm = wave >> 1, wn = wave & 1;
    for (int kt = 0; kt < 6; kt++) {
        __syncthreads();
        stage_tile(Abase + kt * 64, As, tid);
        stage_tile(Bbase + kt * 64, Bs, tid);
        __syncthreads();
        #pragma unroll
        for (int kk = 0; kk < 2; kk++) {
            const int co = kk * 32 + (lane >> 4) * 8;
            bf16x8 a[4], b[4];
            #pragma unroll
            for (int mi = 0; mi < 4; mi++)
                a[mi] = *(const bf16x8*)&As[(wm * 64 + mi * 16 + (lane & 15)) * 64 + co];
            #pragma unroll
            for (int ni = 0; ni < 4; ni++)
                b[ni] = *(const bf16x8*)&Bs[(wn * 64 + ni * 16 + (lane & 15)) * 64 + co];
            #pragma unroll
            for (int mi = 0; mi < 4; mi++)
                #pragma unroll
                for (int ni = 0; ni < 4; ni++)
                    acc[mi][ni] = __builtin_amdgcn_mfma_f32_16x16x32_bf16(a[mi], b[ni], acc[mi][ni], 0, 0, 0);
        }
    }
}

// ---------------- QKV projection ----------------
__global__ __launch_bounds__(256) void qkv_gemm(const u16* __restrict__ Xb, const u16* __restrict__ Wt,
                                                const float* __restrict__ qb, const float* __restrict__ kb,
                                                const float* __restrict__ vb,
                                                u16* __restrict__ Qo, u16* __restrict__ Ko, u16* __restrict__ Vo) {
    const int mBase = blockIdx.x * 128;
    const int nt = blockIdx.y;
    const int proj = nt / 3, nBase = (nt - proj * 3) * 128;
    f32x4 acc[4][4];
    #pragma unroll
    for (int mi = 0; mi < 4; mi++)
        #pragma unroll
        for (int ni = 0; ni < 4; ni++) { f32x4 z = {0.f,0.f,0.f,0.f}; acc[mi][ni] = z; }

    gemm_tile(Xb + mBase * DIM, Wt + proj * WELEM + nBase * DIM, acc);

    const float* bias = (proj==0) ? qb : (proj==1) ? kb : vb;
    u16* Out          = (proj==0) ? Qo : (proj==1) ? Ko : Vo;
    const float scale = (proj==0) ? 0.17677669529663687f : 1.0f;   // fold 1/sqrt(32) into Q
    const int tid = threadIdx.x, wave = tid >> 6, lane = tid & 63;
    const int wm = wave >> 1, wn = wave & 1;

    float bias4[4]; int hh[4], dd[4];
    #pragma unroll
    for (int ni = 0; ni < 4; ni++) {
        int nin = nBase + wn * 64 + ni * 16 + (lane & 15);
        bias4[ni] = bias[nin]; hh[ni] = nin >> 5; dd[ni] = nin & 31;
    }
    #pragma unroll
    for (int mi = 0; mi < 4; mi++) {
        #pragma unroll
        for (int j = 0; j < 4; j++) {
            int gm = mBase + wm * 64 + mi * 16 + ((lane >> 4) << 2) + j;
            int bw = gm / SEQ, s = gm - bw * SEQ;
            int rowbase = (bw * (NH*SEQ) + s) * HD;
            #pragma unroll
            for (int ni = 0; ni < 4; ni++) {
                float val = (acc[mi][ni][j] + bias4[ni]) * scale;
                Out[rowbase + hh[ni] * (SEQ*HD) + dd[ni]] = f2b(val);
            }
        }
    }
}

// ---------------- MFMA attention ----------------
// One wave per (window, head). Block = (wm = w%64, h, jgroup): 4 waves share the
// rpb[h]+mask[wm] panel staged in LDS (pads = -1e30 so padded t rows get p == 0 exactly).
// S^T = mfma(K, Q) per 16x16 tile (D=32 -> single MFMA): lane holds t=(lane>>4)*4+r (+16*ti),
// s=lane&15 (+16*si)  => softmax row-reduce = 16 regs + shfl_xor(16,32).
// P^T -> PV A-frags via v_cvt_pk_bf16_f32 + 2x shfl + select (no LDS round trip).
__global__ __launch_bounds__(256) void attn_mfma(const u16* __restrict__ Qb, const u16* __restrict__ Kb,
                                                 const u16* __restrict__ Vb, const float* __restrict__ rpb,
                                                 const float* __restrict__ mask, u16* __restrict__ Ctx) {
    const int wm = blockIdx.x;                    // 0..63  (w % 64)
    const int h  = blockIdx.y;                    // 0..11
    const int jg = blockIdx.z;                    // 0..7
    const int tid = threadIdx.x, wv = tid >> 6, lane = tid & 63;
    const int r16 = lane & 15, g = lane >> 4;

    __shared__ float comb[64][68];                // +4 pad: float4 reads 2-way-conflict only (free)
    {
        const float* rp = rpb + h * (SEQ*SEQ);
        const float* mp = mask + wm * (SEQ*SEQ);
        for (int idx = tid; idx < 64*64; idx += 256) {
            int s = idx >> 6, t = idx & 63;
            float v = -1e30f;
            if (s < SEQ && t < SEQ) v = rp[s*SEQ + t] + mp[s*SEQ + t];
            comb[s][t] = v;
        }
    }
    __syncthreads();

    const int j = jg * 4 + wv;                    // 0..31
    const int w = j * 64 + wm;
    const u16* Qp = Qb + (w*NH + h) * (SEQ*HD);
    const u16* Kp = Kb + (w*NH + h) * (SEQ*HD);
    const u16* Vp = Vb + (w*NH + h) * (SEQ*HD);
    // NOTE: fragment loads for rows/cols >= 49 read past the panel into the next
    // panel / Wt region — finite deterministic data, masked to p=0 by comb=-1e30.

    bf16x8 kf[4], qf[4];
    #pragma unroll
    for (int ti = 0; ti < 4; ti++) kf[ti] = *(const bf16x8*)&Kp[(ti*16 + r16)*HD + g*8];
    #pragma unroll
    for (int si = 0; si < 4; si++) qf[si] = *(const bf16x8*)&Qp[(si*16 + r16)*HD + g*8];

    f32x4 st[4][4];                               // S^T tiles [ti][si]
    #pragma unroll
    for (int ti = 0; ti < 4; ti++)
        #pragma unroll
        for (int si = 0; si < 4; si++) {
            f32x4 z = {0.f,0.f,0.f,0.f};
            st[ti][si] = __builtin_amdgcn_mfma_f32_16x16x32_bf16(kf[ti], qf[si], z, 0, 0, 0);
        }

    // add comb: S^T[t][s] += comb[s][t];  t = ti*16+g*4+r consecutive in r -> float4
    #pragma unroll
    for (int ti = 0; ti < 4; ti++)
        #pragma unroll
        for (int si = 0; si < 4; si++) {
            const float4 c = *(const float4*)&comb[si*16 + r16][ti*16 + g*4];
            st[ti][si][0] += c.x; st[ti][si][1] += c.y; st[ti][si][2] += c.z; st[ti][si][3] += c.w;
        }

    // softmax over t (per row s): regs (ti,r) + lane bits 4,5
    #pragma unroll
    for (int si = 0; si < 4; si++) {
        float m = st[0][si][0];
        #pragma unroll
        for (int ti = 0; ti < 4; ti++)
            #pragma unroll
            for (int r = 0; r < 4; r++) m = fmaxf(m, st[ti][si][r]);
        m = fmaxf(m, __shfl_xor(m, 16));
        m = fmaxf(m, __shfl_xor(m, 32));
        float sum = 0.f;
        #pragma unroll
        for (int ti = 0; ti < 4; ti++)
            #pragma unroll
            for (int r = 0; r < 4; r++) {
                float p = __expf(st[ti][si][r] - m);
                st[ti][si][r] = p; sum += p;
            }
        sum += __shfl_xor(sum, 16);
        sum += __shfl_xor(sum, 32);
        float rs = 1.0f / sum;
        #pragma unroll
        for (int ti = 0; ti < 4; ti++)
            #pragma unroll
            for (int r = 0; r < 4; r++) st[ti][si][r] *= rs;
    }

    // pack P^T pairs to bf16: pk[ti][si][q] = (bf16(r=2q) lo, bf16(r=2q+1) hi)
    u32 pk[4][4][2];
    #pragma unroll
    for (int ti = 0; ti < 4; ti++)
        #pragma unroll
        for (int si = 0; si < 4; si++)
            #pragma unroll
            for (int q = 0; q < 2; q++) {
                u32 r;
                asm("v_cvt_pk_bf16_f32 %0, %1, %2" : "=v"(r) : "v"(st[ti][si][2*q]), "v"(st[ti][si][2*q+1]));
                pk[ti][si][q] = r;
            }

    // PV A-frags: lane l elem i needs P[s=si*16+(l&15)][t=kc*32+g*8+i]
    //   source: tile kc*2+(l>>5), lane (l&15)+((g&1)<<5)+((i>>2)<<4), pair (i>>1)&1
    bf16x8 pa[2][4];                              // [kc][si]
    const int base_src = r16 + ((g & 1) << 5);
    #pragma unroll
    for (int kc = 0; kc < 2; kc++)
        #pragma unroll
        for (int si = 0; si < 4; si++) {
            union { u32 u[4]; bf16x8 v; } cv;
            #pragma unroll
            for (int jj = 0; jj < 4; jj++) {
                int srcl = base_src + ((jj >> 1) << 4);
                u32 x0 = (u32)__shfl((int)pk[kc*2 + 0][si][jj & 1], srcl);
                u32 x1 = (u32)__shfl((int)pk[kc*2 + 1][si][jj & 1], srcl);
                cv.u[jj] = (lane >= 32) ? x1 : x0;
            }
            pa[kc][si] = cv.v;
        }

    // V B-frags: B[d][t] = V[t][d]; scalar gather (16-lane groups hit 32B segments)
    bf16x8 vf[2][2];                              // [kc][nt]
    #pragma unroll
    for (int kc = 0; kc < 2; kc++)
        #pragma unroll
        for (int nt = 0; nt < 2; nt++) {
            bf16x8 v;
            #pragma unroll
            for (int i = 0; i < 8; i++)
                v[i] = (short)Vp[(kc*32 + g*8 + i)*HD + nt*16 + r16];
            vf[kc][nt] = v;
        }

    f32x4 ct[4][2];                               // ctx tiles [si][nt]
    #pragma unroll
    for (int si = 0; si < 4; si++)
        #pragma unroll
        for (int nt = 0; nt < 2; nt++) {
            f32x4 z = {0.f,0.f,0.f,0.f};
            z = __builtin_amdgcn_mfma_f32_16x16x32_bf16(pa[0][si], vf[0][nt], z, 0, 0, 0);
            ct[si][nt] = __builtin_amdgcn_mfma_f32_16x16x32_bf16(pa[1][si], vf[1][nt], z, 0, 0, 0);
        }

    // store ctx[s][d] -> Ctx[w*49+s][h*32+d]
    #pragma unroll
    for (int si = 0; si < 4; si++)
        #pragma unroll
        for (int r = 0; r < 4; r++) {
            int s = si*16 + g*4 + r;
            if (s < SEQ) {
                #pragma unroll
                for (int nt = 0; nt < 2; nt++)
                    Ctx[(w*SEQ + s)*DIM + h*HD + nt*16 + r16] = f2b(ct[si][nt][r]);
            }
        }
}

// ---------------- output projection ----------------
__global__ __launch_bounds__(256) void oproj_gemm(const u16* __restrict__ Cb, const u16* __restrict__ Wo,
                                                  const float* __restrict__ ob, float* __restrict__ out) {
    const int mBase = blockIdx.x * 128, nBase = blockIdx.y * 128;
    f32x4 acc[4][4];
    #pragma unroll
    for (int mi = 0; mi < 4; mi++)
        #pragma unroll
        for (int ni = 0; ni < 4; ni++) { f32x4 z = {0.f,0.f,0.f,0.f}; acc[mi][ni] = z; }

    gemm_tile(Cb + mBase * DIM, Wo + nBase * DIM, acc);

    const int tid = threadIdx.x, wave = tid >> 6, lane = tid & 63;
    const int wm = wave >> 1, wn = wave & 1;
    float ob4[4]; int gn4[4];
    #pragma unroll
    for (int ni = 0; ni < 4; ni++) {
        gn4[ni] = nBase + wn * 64 + ni * 16 + (lane & 15);
        ob4[ni] = ob[gn4[ni]];
    }
    #pragma unroll
    for (int mi = 0; mi < 4; mi++) {
        #pragma unroll
        for (int j = 0; j < 4; j++) {
            int gm = mBase + wm * 64 + mi * 16 + ((lane >> 4) << 2) + j;
            #pragma unroll
            for (int ni = 0; ni < 4; ni++)
                out[gm * DIM + gn4[ni]] = acc[mi][ni][j] + ob4[ni];
        }
    }
}

// ---------------- launch ----------------
extern "C" void kernel_launch(void* const* d_in, const int* in_sizes, int n_in,
                              void* d_out, int out_size, void* d_ws, size_t ws_size,
                              hipStream_t stream) {
    const float* hs   = (const float*)d_in[0];
    const float* mask = (const float*)d_in[1];
    const float* qW   = (const float*)d_in[2];
    const float* qb   = (const float*)d_in[3];
    const float* kW   = (const float*)d_in[4];
    const float* kb   = (const float*)d_in[5];
    const float* vW   = (const float*)d_in[6];
    const float* vb   = (const float*)d_in[7];
    const float* oW   = (const float*)d_in[8];
    const float* ob   = (const float*)d_in[9];
    const float* bt   = (const float*)d_in[10];
    const int*   ridx = (const int*)d_in[11];
    float* out = (float*)d_out;

    char* ws = (char*)d_ws;
    // layout (bytes): Xbf 77,070,336 (aliased by Ctx after QKV) | Q | K | V | Wt | rpb  (309,576,240 total)
    u16* Xb   = (u16*)(ws);
    u16* Ctx  = (u16*)(ws);                       // alias: X dead after qkv_gemm
    u16* Qb   = (u16*)(ws + 77070336);
    u16* Kb   = (u16*)(ws + 154140672);
    u16* Vb   = (u16*)(ws + 231211008);
    u16* Wt   = (u16*)(ws + 308281344);
    float* rpb = (float*)(ws + 309460992);

    prep_x  <<<37632, 256, 0, stream>>>(hs, Xb);
    prep_w  <<<2304, 256, 0, stream>>>(qW, kW, vW, oW, Wt);
    prep_rpb<<<113, 256, 0, stream>>>(bt, ridx, rpb);
    qkv_gemm<<<dim3(784, 9), 256, 0, stream>>>(Xb, Wt, qb, kb, vb, Qb, Kb, Vb);
    attn_mfma<<<dim3(64, NH, 8), 256, 0, stream>>>(Qb, Kb, Vb, rpb, mask, Ctx);
    oproj_gemm<<<dim3(784, 3), 256, 0, stream>>>(Ctx, Wt + 3 * WELEM, ob, out);
}

// Round 3
// 380.989 us; speedup vs baseline: 2.1100x; 1.0362x over previous
//
#include <hip/hip_runtime.h>

// DonutSwinAttention: hs[2048,49,384] fp32 -> out[2048,49,384] fp32
// Pipeline: prep(X->bf16, W^T->bf16, rpb gather) ; QKV MFMA GEMM ; MFMA attention ; O-proj MFMA GEMM
// R3: T2 LDS XOR-swizzle in gemm_tile (bank conflicts 6.5e7 -> ~0) + T1 XCD-chunked grid swizzle.

typedef unsigned short u16;
typedef unsigned int   u32;
typedef short bf16x8 __attribute__((ext_vector_type(8)));   // MFMA A/B operand (8 bf16)
typedef float f32x4  __attribute__((ext_vector_type(4)));   // MFMA C/D
typedef u16   u16x8  __attribute__((ext_vector_type(8)));
typedef u16   u16x4  __attribute__((ext_vector_type(4)));

#define NWIN   2048
#define SEQ    49
#define DIM    384
#define NH     12
#define HD     32
#define MTOT   (NWIN*SEQ)      // 100352 = 784*128
#define WELEM  (DIM*DIM)       // 147456

__device__ __forceinline__ u16 f2b(float f) {               // fp32 -> bf16 RTN-even
    union { float f; unsigned u; } c; c.f = f;
    unsigned u = c.u;
    u += 0x7FFFu + ((u >> 16) & 1u);
    return (u16)(u >> 16);
}

// ---------------- prep kernels ----------------
__global__ __launch_bounds__(256) void prep_x(const float* __restrict__ X, u16* __restrict__ Xb) {
    int i = blockIdx.x * 256 + threadIdx.x;      // 9,633,792 float4s, exact
    float4 v = ((const float4*)X)[i];
    u16x4 o; o[0]=f2b(v.x); o[1]=f2b(v.y); o[2]=f2b(v.z); o[3]=f2b(v.w);
    ((u16x4*)Xb)[i] = o;
}

__global__ __launch_bounds__(256) void prep_w(const float* __restrict__ qW, const float* __restrict__ kW,
                                              const float* __restrict__ vW, const float* __restrict__ oW,
                                              u16* __restrict__ Wt) {
    int t = blockIdx.x * 256 + threadIdx.x;      // 589,824 exact
    int m = t / WELEM; int rem = t - m * WELEM;
    int k = rem / DIM; int n = rem - k * DIM;
    const float* src = (m==0) ? qW : (m==1) ? kW : (m==2) ? vW : oW;
    Wt[m*WELEM + n*DIM + k] = f2b(src[rem]);     // Wt[m][n][k] = W[k][n]
}

__global__ __launch_bounds__(256) void prep_rpb(const float* __restrict__ bt, const int* __restrict__ ridx,
                                                float* __restrict__ rpb) {
    int t = blockIdx.x * 256 + threadIdx.x;
    if (t >= NH * SEQ * SEQ) return;
    int h = t / (SEQ*SEQ); int st = t - h * (SEQ*SEQ);
    rpb[t] = bt[ridx[st] * NH + h];              // rpb[h][s][t]
}

// ---------------- shared GEMM mainloop: 128x128 tile, K=384, BK=64, 4 waves (2x2) ----------------
// LDS layout: [row][col ^ ((row&7)<<3)] (st_16x32-style XOR swizzle, element units).
// Reads then have 16 lanes spread over 8 distinct 16B slots (2-way = free) instead of
// a 16-way same-bank-set pileup (row stride = 128 B).
__device__ __forceinline__ void stage_tile(const u16* __restrict__ g0, u16* __restrict__ lds, int tid) {
    #pragma unroll
    for (int i = 0; i < 4; i++) {
        int j = tid * 4 + i;                     // 1024 chunks of 8 u16
        int row = j >> 3, c8 = (j & 7) * 8;
        u16x8 v = *(const u16x8*)(g0 + row * DIM + c8);
        *(u16x8*)&lds[row * 64 + (c8 ^ ((row & 7) << 3))] = v;
    }
}

__device__ __forceinline__ void gemm_tile(const u16* __restrict__ Abase, const u16* __restrict__ Bbase,
                                          f32x4 (&acc)[4][4]) {
    __shared__ __align__(16) u16 As[128 * 64];
    __shared__ __align__(16) u16 Bs[128 * 64];
    const int tid = threadIdx.x, wave = tid >> 6, lane = tid & 63;
    const int wm = wave >> 1, wn = wave & 1;
    const int swzl = (lane & 7) << 3;            // fragment rows have row&7 == lane&7
    for (int kt = 0; kt < 6; kt++) {
        __syncthreads();
        stage_tile(Abase + kt * 64, As, tid);
        stage_tile(Bbase + kt * 64, Bs, tid);
        __syncthreads();
        #pragma unroll
        for (int kk = 0; kk < 2; kk++) {
            const int co = (kk * 32 + (lane >> 4) * 8) ^ swzl;
            bf16x8 a[4], b[4];
            #pragma unroll
            for (int mi = 0; mi < 4; mi++)
                a[mi] = *(const bf16x8*)&As[(wm * 64 + mi * 16 + (lane & 15)) * 64 + co];
            #pragma unroll
            for (int ni = 0; ni < 4; ni++)
                b[ni] = *(const bf16x8*)&Bs[(wn * 64 + ni * 16 + (lane & 15)) * 64 + co];
            #pragma unroll
            for (int mi = 0; mi < 4; mi++)
                #pragma unroll
                for (int ni = 0; ni < 4; ni++)
                    acc[mi][ni] = __builtin_amdgcn_mfma_f32_16x16x32_bf16(a[mi], b[ni], acc[mi][ni], 0, 0, 0);
        }
    }
}

// ---------------- QKV projection ----------------
// 1D grid, XCD-chunked swizzle, proj-fastest: the 9 n-tiles sharing one A-tile run
// consecutively on the SAME XCD -> A-tile L2-resident for 8 of 9 reads.
__global__ __launch_bounds__(256) void qkv_gemm(const u16* __restrict__ Xb, const u16* __restrict__ Wt,
                                                const float* __restrict__ qb, const float* __restrict__ kb,
                                                const float* __restrict__ vb,
                                                u16* __restrict__ Qo, u16* __restrict__ Ko, u16* __restrict__ Vo) {
    const int bid = blockIdx.x;                   // 0..7055 (= 784*9, %8 == 0)
    const int swz = (bid & 7) * 882 + (bid >> 3);
    const int mTile = swz / 9, p = swz - mTile * 9;
    const int mBase = mTile * 128;
    const int proj = p / 3, nBase = (p - proj * 3) * 128;
    f32x4 acc[4][4];
    #pragma unroll
    for (int mi = 0; mi < 4; mi++)
        #pragma unroll
        for (int ni = 0; ni < 4; ni++) { f32x4 z = {0.f,0.f,0.f,0.f}; acc[mi][ni] = z; }

    gemm_tile(Xb + mBase * DIM, Wt + proj * WELEM + nBase * DIM, acc);

    const float* bias = (proj==0) ? qb : (proj==1) ? kb : vb;
    u16* Out          = (proj==0) ? Qo : (proj==1) ? Ko : Vo;
    const float scale = (proj==0) ? 0.17677669529663687f : 1.0f;   // fold 1/sqrt(32) into Q
    const int tid = threadIdx.x, wave = tid >> 6, lane = tid & 63;
    const int wm = wave >> 1, wn = wave & 1;

    float bias4[4]; int hh[4], dd[4];
    #pragma unroll
    for (int ni = 0; ni < 4; ni++) {
        int nin = nBase + wn * 64 + ni * 16 + (lane & 15);
        bias4[ni] = bias[nin]; hh[ni] = nin >> 5; dd[ni] = nin & 31;
    }
    #pragma unroll
    for (int mi = 0; mi < 4; mi++) {
        #pragma unroll
        for (int j = 0; j < 4; j++) {
            int gm = mBase + wm * 64 + mi * 16 + ((lane >> 4) << 2) + j;
            int bw = gm / SEQ, s = gm - bw * SEQ;
            int rowbase = (bw * (NH*SEQ) + s) * HD;
            #pragma unroll
            for (int ni = 0; ni < 4; ni++) {
                float val = (acc[mi][ni][j] + bias4[ni]) * scale;
                Out[rowbase + hh[ni] * (SEQ*HD) + dd[ni]] = f2b(val);
            }
        }
    }
}

// ---------------- MFMA attention ----------------
// One wave per (window, head). Block = (wm = w%64, h, jgroup): 4 waves share the
// rpb[h]+mask[wm] panel staged in LDS (pads = -1e30 so padded t rows get p == 0 exactly).
__global__ __launch_bounds__(256) void attn_mfma(const u16* __restrict__ Qb, const u16* __restrict__ Kb,
                                                 const u16* __restrict__ Vb, const float* __restrict__ rpb,
                                                 const float* __restrict__ mask, u16* __restrict__ Ctx) {
    const int wm = blockIdx.x;                    // 0..63  (w % 64)
    const int h  = blockIdx.y;                    // 0..11
    const int jg = blockIdx.z;                    // 0..7
    const int tid = threadIdx.x, wv = tid >> 6, lane = tid & 63;
    const int r16 = lane & 15, g = lane >> 4;

    __shared__ float comb[64][68];
    {
        const float* rp = rpb + h * (SEQ*SEQ);
        const float* mp = mask + wm * (SEQ*SEQ);
        for (int idx = tid; idx < 64*64; idx += 256) {
            int s = idx >> 6, t = idx & 63;
            float v = -1e30f;
            if (s < SEQ && t < SEQ) v = rp[s*SEQ + t] + mp[s*SEQ + t];
            comb[s][t] = v;
        }
    }
    __syncthreads();

    const int j = jg * 4 + wv;                    // 0..31
    const int w = j * 64 + wm;
    const u16* Qp = Qb + (w*NH + h) * (SEQ*HD);
    const u16* Kp = Kb + (w*NH + h) * (SEQ*HD);
    const u16* Vp = Vb + (w*NH + h) * (SEQ*HD);

    bf16x8 kf[4], qf[4];
    #pragma unroll
    for (int ti = 0; ti < 4; ti++) kf[ti] = *(const bf16x8*)&Kp[(ti*16 + r16)*HD + g*8];
    #pragma unroll
    for (int si = 0; si < 4; si++) qf[si] = *(const bf16x8*)&Qp[(si*16 + r16)*HD + g*8];

    f32x4 st[4][4];                               // S^T tiles [ti][si]
    #pragma unroll
    for (int ti = 0; ti < 4; ti++)
        #pragma unroll
        for (int si = 0; si < 4; si++) {
            f32x4 z = {0.f,0.f,0.f,0.f};
            st[ti][si] = __builtin_amdgcn_mfma_f32_16x16x32_bf16(kf[ti], qf[si], z, 0, 0, 0);
        }

    #pragma unroll
    for (int ti = 0; ti < 4; ti++)
        #pragma unroll
        for (int si = 0; si < 4; si++) {
            const float4 c = *(const float4*)&comb[si*16 + r16][ti*16 + g*4];
            st[ti][si][0] += c.x; st[ti][si][1] += c.y; st[ti][si][2] += c.z; st[ti][si][3] += c.w;
        }

    #pragma unroll
    for (int si = 0; si < 4; si++) {
        float m = st[0][si][0];
        #pragma unroll
        for (int ti = 0; ti < 4; ti++)
            #pragma unroll
            for (int r = 0; r < 4; r++) m = fmaxf(m, st[ti][si][r]);
        m = fmaxf(m, __shfl_xor(m, 16));
        m = fmaxf(m, __shfl_xor(m, 32));
        float sum = 0.f;
        #pragma unroll
        for (int ti = 0; ti < 4; ti++)
            #pragma unroll
            for (int r = 0; r < 4; r++) {
                float p = __expf(st[ti][si][r] - m);
                st[ti][si][r] = p; sum += p;
            }
        sum += __shfl_xor(sum, 16);
        sum += __shfl_xor(sum, 32);
        float rs = 1.0f / sum;
        #pragma unroll
        for (int ti = 0; ti < 4; ti++)
            #pragma unroll
            for (int r = 0; r < 4; r++) st[ti][si][r] *= rs;
    }

    u32 pk[4][4][2];
    #pragma unroll
    for (int ti = 0; ti < 4; ti++)
        #pragma unroll
        for (int si = 0; si < 4; si++)
            #pragma unroll
            for (int q = 0; q < 2; q++) {
                u32 r;
                asm("v_cvt_pk_bf16_f32 %0, %1, %2" : "=v"(r) : "v"(st[ti][si][2*q]), "v"(st[ti][si][2*q+1]));
                pk[ti][si][q] = r;
            }

    bf16x8 pa[2][4];                              // [kc][si]
    const int base_src = r16 + ((g & 1) << 5);
    #pragma unroll
    for (int kc = 0; kc < 2; kc++)
        #pragma unroll
        for (int si = 0; si < 4; si++) {
            union { u32 u[4]; bf16x8 v; } cv;
            #pragma unroll
            for (int jj = 0; jj < 4; jj++) {
                int srcl = base_src + ((jj >> 1) << 4);
                u32 x0 = (u32)__shfl((int)pk[kc*2 + 0][si][jj & 1], srcl);
                u32 x1 = (u32)__shfl((int)pk[kc*2 + 1][si][jj & 1], srcl);
                cv.u[jj] = (lane >= 32) ? x1 : x0;
            }
            pa[kc][si] = cv.v;
        }

    bf16x8 vf[2][2];                              // [kc][nt]
    #pragma unroll
    for (int kc = 0; kc < 2; kc++)
        #pragma unroll
        for (int nt = 0; nt < 2; nt++) {
            bf16x8 v;
            #pragma unroll
            for (int i = 0; i < 8; i++)
                v[i] = (short)Vp[(kc*32 + g*8 + i)*HD + nt*16 + r16];
            vf[kc][nt] = v;
        }

    f32x4 ct[4][2];                               // ctx tiles [si][nt]
    #pragma unroll
    for (int si = 0; si < 4; si++)
        #pragma unroll
        for (int nt = 0; nt < 2; nt++) {
            f32x4 z = {0.f,0.f,0.f,0.f};
            z = __builtin_amdgcn_mfma_f32_16x16x32_bf16(pa[0][si], vf[0][nt], z, 0, 0, 0);
            ct[si][nt] = __builtin_amdgcn_mfma_f32_16x16x32_bf16(pa[1][si], vf[1][nt], z, 0, 0, 0);
        }

    #pragma unroll
    for (int si = 0; si < 4; si++)
        #pragma unroll
        for (int r = 0; r < 4; r++) {
            int s = si*16 + g*4 + r;
            if (s < SEQ) {
                #pragma unroll
                for (int nt = 0; nt < 2; nt++)
                    Ctx[(w*SEQ + s)*DIM + h*HD + nt*16 + r16] = f2b(ct[si][nt][r]);
            }
        }
}

// ---------------- output projection ----------------
__global__ __launch_bounds__(256) void oproj_gemm(const u16* __restrict__ Cb, const u16* __restrict__ Wo,
                                                  const float* __restrict__ ob, float* __restrict__ out) {
    const int bid = blockIdx.x;                   // 0..2351 (= 784*3, %8 == 0)
    const int swz = (bid & 7) * 294 + (bid >> 3);
    const int mTile = swz / 3, nTile = swz - mTile * 3;
    const int mBase = mTile * 128, nBase = nTile * 128;
    f32x4 acc[4][4];
    #pragma unroll
    for (int mi = 0; mi < 4; mi++)
        #pragma unroll
        for (int ni = 0; ni < 4; ni++) { f32x4 z = {0.f,0.f,0.f,0.f}; acc[mi][ni] = z; }

    gemm_tile(Cb + mBase * DIM, Wo + nBase * DIM, acc);

    const int tid = threadIdx.x, wave = tid >> 6, lane = tid & 63;
    const int wm = wave >> 1, wn = wave & 1;
    float ob4[4]; int gn4[4];
    #pragma unroll
    for (int ni = 0; ni < 4; ni++) {
        gn4[ni] = nBase + wn * 64 + ni * 16 + (lane & 15);
        ob4[ni] = ob[gn4[ni]];
    }
    #pragma unroll
    for (int mi = 0; mi < 4; mi++) {
        #pragma unroll
        for (int j = 0; j < 4; j++) {
            int gm = mBase + wm * 64 + mi * 16 + ((lane >> 4) << 2) + j;
            #pragma unroll
            for (int ni = 0; ni < 4; ni++)
                out[gm * DIM + gn4[ni]] = acc[mi][ni][j] + ob4[ni];
        }
    }
}

// ---------------- launch ----------------
extern "C" void kernel_launch(void* const* d_in, const int* in_sizes, int n_in,
                              void* d_out, int out_size, void* d_ws, size_t ws_size,
                              hipStream_t stream) {
    const float* hs   = (const float*)d_in[0];
    const float* mask = (const float*)d_in[1];
    const float* qW   = (const float*)d_in[2];
    const float* qb   = (const float*)d_in[3];
    const float* kW   = (const float*)d_in[4];
    const float* kb   = (const float*)d_in[5];
    const float* vW   = (const float*)d_in[6];
    const float* vb   = (const float*)d_in[7];
    const float* oW   = (const float*)d_in[8];
    const float* ob   = (const float*)d_in[9];
    const float* bt   = (const float*)d_in[10];
    const int*   ridx = (const int*)d_in[11];
    float* out = (float*)d_out;

    char* ws = (char*)d_ws;
    // layout (bytes): Xbf 77,070,336 (aliased by Ctx after QKV) | Q | K | V | Wt | rpb  (309,576,240 total)
    u16* Xb   = (u16*)(ws);
    u16* Ctx  = (u16*)(ws);                       // alias: X dead after qkv_gemm
    u16* Qb   = (u16*)(ws + 77070336);
    u16* Kb   = (u16*)(ws + 154140672);
    u16* Vb   = (u16*)(ws + 231211008);
    u16* Wt   = (u16*)(ws + 308281344);
    float* rpb = (float*)(ws + 309460992);

    prep_x  <<<37632, 256, 0, stream>>>(hs, Xb);
    prep_w  <<<2304, 256, 0, stream>>>(qW, kW, vW, oW, Wt);
    prep_rpb<<<113, 256, 0, stream>>>(bt, ridx, rpb);
    qkv_gemm<<<7056, 256, 0, stream>>>(Xb, Wt, qb, kb, vb, Qb, Kb, Vb);
    attn_mfma<<<dim3(64, NH, 8), 256, 0, stream>>>(Qb, Kb, Vb, rpb, mask, Ctx);
    oproj_gemm<<<2352, 256, 0, stream>>>(Ctx, Wt + 3 * WELEM, ob, out);
}

// Round 4
// 353.263 us; speedup vs baseline: 2.2756x; 1.0785x over previous
//
#include <hip/hip_runtime.h>

// DonutSwinAttention: hs[2048,49,384] fp32 -> out[2048,49,384] fp32
// Pipeline: prep(X->bf16, W^T->bf16, rpb gather) ; QKV MFMA GEMM ; MFMA attention ; O-proj MFMA GEMM
// R4: global_load_lds width-16 staging (pre-swizzled global source, linear LDS dest,
//     swizzled read side unchanged — rule #21 both-sides involution).

typedef unsigned short u16;
typedef unsigned int   u32;
typedef short bf16x8 __attribute__((ext_vector_type(8)));   // MFMA A/B operand (8 bf16)
typedef float f32x4  __attribute__((ext_vector_type(4)));   // MFMA C/D
typedef u16   u16x8  __attribute__((ext_vector_type(8)));
typedef u16   u16x4  __attribute__((ext_vector_type(4)));

#define NWIN   2048
#define SEQ    49
#define DIM    384
#define NH     12
#define HD     32
#define MTOT   (NWIN*SEQ)      // 100352 = 784*128
#define WELEM  (DIM*DIM)       // 147456

__device__ __forceinline__ u16 f2b(float f) {               // fp32 -> bf16 RTN-even
    union { float f; unsigned u; } c; c.f = f;
    unsigned u = c.u;
    u += 0x7FFFu + ((u >> 16) & 1u);
    return (u16)(u >> 16);
}

// ---------------- prep kernels ----------------
__global__ __launch_bounds__(256) void prep_x(const float* __restrict__ X, u16* __restrict__ Xb) {
    int i = blockIdx.x * 256 + threadIdx.x;      // 9,633,792 float4s, exact
    float4 v = ((const float4*)X)[i];
    u16x4 o; o[0]=f2b(v.x); o[1]=f2b(v.y); o[2]=f2b(v.z); o[3]=f2b(v.w);
    ((u16x4*)Xb)[i] = o;
}

__global__ __launch_bounds__(256) void prep_w(const float* __restrict__ qW, const float* __restrict__ kW,
                                              const float* __restrict__ vW, const float* __restrict__ oW,
                                              u16* __restrict__ Wt) {
    int t = blockIdx.x * 256 + threadIdx.x;      // 589,824 exact
    int m = t / WELEM; int rem = t - m * WELEM;
    int k = rem / DIM; int n = rem - k * DIM;
    const float* src = (m==0) ? qW : (m==1) ? kW : (m==2) ? vW : oW;
    Wt[m*WELEM + n*DIM + k] = f2b(src[rem]);     // Wt[m][n][k] = W[k][n]
}

__global__ __launch_bounds__(256) void prep_rpb(const float* __restrict__ bt, const int* __restrict__ ridx,
                                                float* __restrict__ rpb) {
    int t = blockIdx.x * 256 + threadIdx.x;
    if (t >= NH * SEQ * SEQ) return;
    int h = t / (SEQ*SEQ); int st = t - h * (SEQ*SEQ);
    rpb[t] = bt[ridx[st] * NH + h];              // rpb[h][s][t]
}

// ---------------- shared GEMM mainloop: 128x128 tile, K=384, BK=64, 4 waves (2x2) ----------------
// LDS holds [row][col] with LDS[row][x] = G[row][x ^ ((row&7)<<3)] (element units).
// Staged via global_load_lds dwordx4: LDS dest is linear (wave base + lane*16B, HW
// requirement), the swizzle is applied to the per-lane GLOBAL source address.
__device__ __forceinline__ void gload_lds16(const void* g, void* l) {
    __builtin_amdgcn_global_load_lds((const __attribute__((address_space(1))) void*)g,
                                     (__attribute__((address_space(3))) void*)l, 16, 0, 0);
}

__device__ __forceinline__ void stage_tile_async(const u16* __restrict__ g0, u16* lds, int wv, int lane) {
    const int r8   = lane >> 3;                         // row & 7 within every 8-row stripe
    const int scol = ((lane & 7) * 8) ^ (r8 << 3);      // pre-swizzled source col (elements)
    const u16* src = g0 + (wv * 8 + r8) * DIM + scol;
    u16*       dst = lds + wv * 512 + lane * 8;         // linear: wave base + lane*16B
    #pragma unroll
    for (int i = 0; i < 4; i++)                         // rows i*32 + wv*8 + r8
        gload_lds16(src + i * 32 * DIM, dst + i * 2048);
}

__device__ __forceinline__ void gemm_tile(const u16* __restrict__ Abase, const u16* __restrict__ Bbase,
                                          f32x4 (&acc)[4][4]) {
    __shared__ __align__(16) u16 As[128 * 64];
    __shared__ __align__(16) u16 Bs[128 * 64];
    const int tid = threadIdx.x, wave = tid >> 6, lane = tid & 63;
    const int wm = wave >> 1, wn = wave & 1;
    const int swzl = (lane & 7) << 3;            // fragment rows have row&7 == lane&7
    for (int kt = 0; kt < 6; kt++) {
        __syncthreads();                          // prev ds_reads done before DMA overwrite
        stage_tile_async(Abase + kt * 64, As, wave, lane);
        stage_tile_async(Bbase + kt * 64, Bs, wave, lane);
        __syncthreads();                          // drains vmcnt(0): DMA writes visible
        #pragma unroll
        for (int kk = 0; kk < 2; kk++) {
            const int co = (kk * 32 + (lane >> 4) * 8) ^ swzl;
            bf16x8 a[4], b[4];
            #pragma unroll
            for (int mi = 0; mi < 4; mi++)
                a[mi] = *(const bf16x8*)&As[(wm * 64 + mi * 16 + (lane & 15)) * 64 + co];
            #pragma unroll
            for (int ni = 0; ni < 4; ni++)
                b[ni] = *(const bf16x8*)&Bs[(wn * 64 + ni * 16 + (lane & 15)) * 64 + co];
            #pragma unroll
            for (int mi = 0; mi < 4; mi++)
                #pragma unroll
                for (int ni = 0; ni < 4; ni++)
                    acc[mi][ni] = __builtin_amdgcn_mfma_f32_16x16x32_bf16(a[mi], b[ni], acc[mi][ni], 0, 0, 0);
        }
    }
}

// ---------------- QKV projection ----------------
// 1D grid, XCD-chunked swizzle, proj-fastest: the 9 n-tiles sharing one A-tile run
// consecutively on the SAME XCD -> A-tile L2-resident for 8 of 9 reads.
__global__ __launch_bounds__(256) void qkv_gemm(const u16* __restrict__ Xb, const u16* __restrict__ Wt,
                                                const float* __restrict__ qb, const float* __restrict__ kb,
                                                const float* __restrict__ vb,
                                                u16* __restrict__ Qo, u16* __restrict__ Ko, u16* __restrict__ Vo) {
    const int bid = blockIdx.x;                   // 0..7055 (= 784*9, %8 == 0)
    const int swz = (bid & 7) * 882 + (bid >> 3);
    const int mTile = swz / 9, p = swz - mTile * 9;
    const int mBase = mTile * 128;
    const int proj = p / 3, nBase = (p - proj * 3) * 128;
    f32x4 acc[4][4];
    #pragma unroll
    for (int mi = 0; mi < 4; mi++)
        #pragma unroll
        for (int ni = 0; ni < 4; ni++) { f32x4 z = {0.f,0.f,0.f,0.f}; acc[mi][ni] = z; }

    gemm_tile(Xb + mBase * DIM, Wt + proj * WELEM + nBase * DIM, acc);

    const float* bias = (proj==0) ? qb : (proj==1) ? kb : vb;
    u16* Out          = (proj==0) ? Qo : (proj==1) ? Ko : Vo;
    const float scale = (proj==0) ? 0.17677669529663687f : 1.0f;   // fold 1/sqrt(32) into Q
    const int tid = threadIdx.x, wave = tid >> 6, lane = tid & 63;
    const int wm = wave >> 1, wn = wave & 1;

    float bias4[4]; int hh[4], dd[4];
    #pragma unroll
    for (int ni = 0; ni < 4; ni++) {
        int nin = nBase + wn * 64 + ni * 16 + (lane & 15);
        bias4[ni] = bias[nin]; hh[ni] = nin >> 5; dd[ni] = nin & 31;
    }
    #pragma unroll
    for (int mi = 0; mi < 4; mi++) {
        #pragma unroll
        for (int j = 0; j < 4; j++) {
            int gm = mBase + wm * 64 + mi * 16 + ((lane >> 4) << 2) + j;
            int bw = gm / SEQ, s = gm - bw * SEQ;
            int rowbase = (bw * (NH*SEQ) + s) * HD;
            #pragma unroll
            for (int ni = 0; ni < 4; ni++) {
                float val = (acc[mi][ni][j] + bias4[ni]) * scale;
                Out[rowbase + hh[ni] * (SEQ*HD) + dd[ni]] = f2b(val);
            }
        }
    }
}

// ---------------- MFMA attention ----------------
// One wave per (window, head). Block = (wm = w%64, h, jgroup): 4 waves share the
// rpb[h]+mask[wm] panel staged in LDS (pads = -1e30 so padded t rows get p == 0 exactly).
__global__ __launch_bounds__(256) void attn_mfma(const u16* __restrict__ Qb, const u16* __restrict__ Kb,
                                                 const u16* __restrict__ Vb, const float* __restrict__ rpb,
                                                 const float* __restrict__ mask, u16* __restrict__ Ctx) {
    const int wm = blockIdx.x;                    // 0..63  (w % 64)
    const int h  = blockIdx.y;                    // 0..11
    const int jg = blockIdx.z;                    // 0..7
    const int tid = threadIdx.x, wv = tid >> 6, lane = tid & 63;
    const int r16 = lane & 15, g = lane >> 4;

    __shared__ float comb[64][68];
    {
        const float* rp = rpb + h * (SEQ*SEQ);
        const float* mp = mask + wm * (SEQ*SEQ);
        for (int idx = tid; idx < 64*64; idx += 256) {
            int s = idx >> 6, t = idx & 63;
            float v = -1e30f;
            if (s < SEQ && t < SEQ) v = rp[s*SEQ + t] + mp[s*SEQ + t];
            comb[s][t] = v;
        }
    }
    __syncthreads();

    const int j = jg * 4 + wv;                    // 0..31
    const int w = j * 64 + wm;
    const u16* Qp = Qb + (w*NH + h) * (SEQ*HD);
    const u16* Kp = Kb + (w*NH + h) * (SEQ*HD);
    const u16* Vp = Vb + (w*NH + h) * (SEQ*HD);

    bf16x8 kf[4], qf[4];
    #pragma unroll
    for (int ti = 0; ti < 4; ti++) kf[ti] = *(const bf16x8*)&Kp[(ti*16 + r16)*HD + g*8];
    #pragma unroll
    for (int si = 0; si < 4; si++) qf[si] = *(const bf16x8*)&Qp[(si*16 + r16)*HD + g*8];

    f32x4 st[4][4];                               // S^T tiles [ti][si]
    #pragma unroll
    for (int ti = 0; ti < 4; ti++)
        #pragma unroll
        for (int si = 0; si < 4; si++) {
            f32x4 z = {0.f,0.f,0.f,0.f};
            st[ti][si] = __builtin_amdgcn_mfma_f32_16x16x32_bf16(kf[ti], qf[si], z, 0, 0, 0);
        }

    #pragma unroll
    for (int ti = 0; ti < 4; ti++)
        #pragma unroll
        for (int si = 0; si < 4; si++) {
            const float4 c = *(const float4*)&comb[si*16 + r16][ti*16 + g*4];
            st[ti][si][0] += c.x; st[ti][si][1] += c.y; st[ti][si][2] += c.z; st[ti][si][3] += c.w;
        }

    #pragma unroll
    for (int si = 0; si < 4; si++) {
        float m = st[0][si][0];
        #pragma unroll
        for (int ti = 0; ti < 4; ti++)
            #pragma unroll
            for (int r = 0; r < 4; r++) m = fmaxf(m, st[ti][si][r]);
        m = fmaxf(m, __shfl_xor(m, 16));
        m = fmaxf(m, __shfl_xor(m, 32));
        float sum = 0.f;
        #pragma unroll
        for (int ti = 0; ti < 4; ti++)
            #pragma unroll
            for (int r = 0; r < 4; r++) {
                float p = __expf(st[ti][si][r] - m);
                st[ti][si][r] = p; sum += p;
            }
        sum += __shfl_xor(sum, 16);
        sum += __shfl_xor(sum, 32);
        float rs = 1.0f / sum;
        #pragma unroll
        for (int ti = 0; ti < 4; ti++)
            #pragma unroll
            for (int r = 0; r < 4; r++) st[ti][si][r] *= rs;
    }

    u32 pk[4][4][2];
    #pragma unroll
    for (int ti = 0; ti < 4; ti++)
        #pragma unroll
        for (int si = 0; si < 4; si++)
            #pragma unroll
            for (int q = 0; q < 2; q++) {
                u32 r;
                asm("v_cvt_pk_bf16_f32 %0, %1, %2" : "=v"(r) : "v"(st[ti][si][2*q]), "v"(st[ti][si][2*q+1]));
                pk[ti][si][q] = r;
            }

    bf16x8 pa[2][4];                              // [kc][si]
    const int base_src = r16 + ((g & 1) << 5);
    #pragma unroll
    for (int kc = 0; kc < 2; kc++)
        #pragma unroll
        for (int si = 0; si < 4; si++) {
            union { u32 u[4]; bf16x8 v; } cv;
            #pragma unroll
            for (int jj = 0; jj < 4; jj++) {
                int srcl = base_src + ((jj >> 1) << 4);
                u32 x0 = (u32)__shfl((int)pk[kc*2 + 0][si][jj & 1], srcl);
                u32 x1 = (u32)__shfl((int)pk[kc*2 + 1][si][jj & 1], srcl);
                cv.u[jj] = (lane >= 32) ? x1 : x0;
            }
            pa[kc][si] = cv.v;
        }

    bf16x8 vf[2][2];                              // [kc][nt]
    #pragma unroll
    for (int kc = 0; kc < 2; kc++)
        #pragma unroll
        for (int nt = 0; nt < 2; nt++) {
            bf16x8 v;
            #pragma unroll
            for (int i = 0; i < 8; i++)
                v[i] = (short)Vp[(kc*32 + g*8 + i)*HD + nt*16 + r16];
            vf[kc][nt] = v;
        }

    f32x4 ct[4][2];                               // ctx tiles [si][nt]
    #pragma unroll
    for (int si = 0; si < 4; si++)
        #pragma unroll
        for (int nt = 0; nt < 2; nt++) {
            f32x4 z = {0.f,0.f,0.f,0.f};
            z = __builtin_amdgcn_mfma_f32_16x16x32_bf16(pa[0][si], vf[0][nt], z, 0, 0, 0);
            ct[si][nt] = __builtin_amdgcn_mfma_f32_16x16x32_bf16(pa[1][si], vf[1][nt], z, 0, 0, 0);
        }

    #pragma unroll
    for (int si = 0; si < 4; si++)
        #pragma unroll
        for (int r = 0; r < 4; r++) {
            int s = si*16 + g*4 + r;
            if (s < SEQ) {
                #pragma unroll
                for (int nt = 0; nt < 2; nt++)
                    Ctx[(w*SEQ + s)*DIM + h*HD + nt*16 + r16] = f2b(ct[si][nt][r]);
            }
        }
}

// ---------------- output projection ----------------
__global__ __launch_bounds__(256) void oproj_gemm(const u16* __restrict__ Cb, const u16* __restrict__ Wo,
                                                  const float* __restrict__ ob, float* __restrict__ out) {
    const int bid = blockIdx.x;                   // 0..2351 (= 784*3, %8 == 0)
    const int swz = (bid & 7) * 294 + (bid >> 3);
    const int mTile = swz / 3, nTile = swz - mTile * 3;
    const int mBase = mTile * 128, nBase = nTile * 128;
    f32x4 acc[4][4];
    #pragma unroll
    for (int mi = 0; mi < 4; mi++)
        #pragma unroll
        for (int ni = 0; ni < 4; ni++) { f32x4 z = {0.f,0.f,0.f,0.f}; acc[mi][ni] = z; }

    gemm_tile(Cb + mBase * DIM, Wo + nBase * DIM, acc);

    const int tid = threadIdx.x, wave = tid >> 6, lane = tid & 63;
    const int wm = wave >> 1, wn = wave & 1;
    float ob4[4]; int gn4[4];
    #pragma unroll
    for (int ni = 0; ni < 4; ni++) {
        gn4[ni] = nBase + wn * 64 + ni * 16 + (lane & 15);
        ob4[ni] = ob[gn4[ni]];
    }
    #pragma unroll
    for (int mi = 0; mi < 4; mi++) {
        #pragma unroll
        for (int j = 0; j < 4; j++) {
            int gm = mBase + wm * 64 + mi * 16 + ((lane >> 4) << 2) + j;
            #pragma unroll
            for (int ni = 0; ni < 4; ni++)
                out[gm * DIM + gn4[ni]] = acc[mi][ni][j] + ob4[ni];
        }
    }
}

// ---------------- launch ----------------
extern "C" void kernel_launch(void* const* d_in, const int* in_sizes, int n_in,
                              void* d_out, int out_size, void* d_ws, size_t ws_size,
                              hipStream_t stream) {
    const float* hs   = (const float*)d_in[0];
    const float* mask = (const float*)d_in[1];
    const float* qW   = (const float*)d_in[2];
    const float* qb   = (const float*)d_in[3];
    const float* kW   = (const float*)d_in[4];
    const float* kb   = (const float*)d_in[5];
    const float* vW   = (const float*)d_in[6];
    const float* vb   = (const float*)d_in[7];
    const float* oW   = (const float*)d_in[8];
    const float* ob   = (const float*)d_in[9];
    const float* bt   = (const float*)d_in[10];
    const int*   ridx = (const int*)d_in[11];
    float* out = (float*)d_out;

    char* ws = (char*)d_ws;
    // layout (bytes): Xbf 77,070,336 (aliased by Ctx after QKV) | Q | K | V | Wt | rpb  (309,576,240 total)
    u16* Xb   = (u16*)(ws);
    u16* Ctx  = (u16*)(ws);                       // alias: X dead after qkv_gemm
    u16* Qb   = (u16*)(ws + 77070336);
    u16* Kb   = (u16*)(ws + 154140672);
    u16* Vb   = (u16*)(ws + 231211008);
    u16* Wt   = (u16*)(ws + 308281344);
    float* rpb = (float*)(ws + 309460992);

    prep_x  <<<37632, 256, 0, stream>>>(hs, Xb);
    prep_w  <<<2304, 256, 0, stream>>>(qW, kW, vW, oW, Wt);
    prep_rpb<<<113, 256, 0, stream>>>(bt, ridx, rpb);
    qkv_gemm<<<7056, 256, 0, stream>>>(Xb, Wt, qb, kb, vb, Qb, Kb, Vb);
    attn_mfma<<<dim3(64, NH, 8), 256, 0, stream>>>(Qb, Kb, Vb, rpb, mask, Ctx);
    oproj_gemm<<<2352, 256, 0, stream>>>(Ctx, Wt + 3 * WELEM, ob, out);
}